// Round 13
// baseline (118.892 us; speedup 1.0000x reference)
//
#include <hip/hip_runtime.h>
#include <hip/hip_bf16.h>
#include <math.h>

#define N_NODES 50000
#define N_EDGES 600000
#define N_GRAPHS 512
#define LN_EPS 1e-5f
#define CAP 64
#define NPB 128                    // nodes per bin
#define NBINS ((N_NODES + NPB - 1) / NPB)   // 391
#define BCAP 2048                  // edges per bin bucket
#define BPAD 16                    // bin counter padding (64B line each)
#define PREP_BLOCKS ((N_NODES * 8 + 255) / 256)
#define P1_EPB 4096                // edges per bin_scatter block
#define P1_BLOCKS ((N_EDGES + P1_EPB - 1) / P1_EPB)   // 147

typedef short bf16x8 __attribute__((ext_vector_type(8)));
typedef float f32x4 __attribute__((ext_vector_type(4)));

__device__ __forceinline__ unsigned short f2bf(float f) {
    unsigned int x = __float_as_uint(f);
    return (unsigned short)((x + 0x7fffu + ((x >> 16) & 1u)) >> 16);
}
__device__ __forceinline__ float bflo(unsigned int u) { return __uint_as_float(u << 16); }
__device__ __forceinline__ float bfhi(unsigned int u) { return __uint_as_float(u & 0xffff0000u); }

// ---------------------------------------------------------------------------
// prep: Xh1 build (uint4 stores) + weight concat + starts + binCnt zero
__global__ __launch_bounds__(256) void prep_kernel(
    const float* __restrict__ x, const float* __restrict__ xdims,
    const int* __restrict__ stt, const float* __restrict__ st_emb,
    const float* __restrict__ Wl1, const float* __restrict__ Wr1,
    const float* __restrict__ Wl2, const float* __restrict__ Wr2,
    const int* __restrict__ batch,
    unsigned short* __restrict__ Xh1, unsigned short* __restrict__ Wc1,
    unsigned short* __restrict__ Wc2, int* __restrict__ binCnt,
    int* __restrict__ starts)
{
    int idx = blockIdx.x * 256 + threadIdx.x;

    // job A: Xh1[n][c], 8 cols/thread, one uint4 store
    if (idx < N_NODES * 8) {
        int n = idx >> 3;
        int c0 = (idx & 7) * 8;
        float vv[8];
        #pragma unroll
        for (int j = 0; j < 8; ++j) {
            int c = c0 + j;
            float v;
            if (c < 29)       v = x[n * 29 + c];
            else if (c < 32)  v = xdims[n * 3 + (c - 29)];
            else if (c < 44)  v = st_emb[stt[n] * 12 + (c - 32)];
            else              v = 0.f;
            vv[j] = v;
        }
        uint4 p;
        p.x = (unsigned int)f2bf(vv[0]) | ((unsigned int)f2bf(vv[1]) << 16);
        p.y = (unsigned int)f2bf(vv[2]) | ((unsigned int)f2bf(vv[3]) << 16);
        p.z = (unsigned int)f2bf(vv[4]) | ((unsigned int)f2bf(vv[5]) << 16);
        p.w = (unsigned int)f2bf(vv[6]) | ((unsigned int)f2bf(vv[7]) << 16);
        ((uint4*)Xh1)[idx] = p;
    }
    // job B: Wc1 row f = [Wr1(44) | 0x20 | Wl1(44) | 0x20]
    if (idx < 128 * 128) {
        int f = idx >> 7, k = idx & 127;
        float v;
        if (k < 44)        v = Wr1[f * 44 + k];
        else if (k < 64)   v = 0.f;
        else if (k < 108)  v = Wl1[f * 44 + (k - 64)];
        else               v = 0.f;
        Wc1[idx] = f2bf(v);
    }
    // job C: Wc2 row f = [Wr2(128) | Wl2(128)]
    if (idx < 128 * 256) {
        int f = idx >> 8, k = idx & 255;
        float v = (k < 128) ? Wr2[f * 128 + k] : Wl2[f * 128 + (k - 128)];
        Wc2[idx] = f2bf(v);
    }
    // job D: graph starts from sorted batch
    if (idx < N_NODES) {
        int b = batch[idx];
        int pb = (idx == 0) ? -1 : batch[idx - 1];
        for (int g = pb + 1; g <= b; ++g) starts[g] = idx;
        if (idx == N_NODES - 1)
            for (int g = b + 1; g <= N_GRAPHS; ++g) starts[g] = N_NODES;
    }
    // job E: zero padded bin counters
    if (idx < NBINS * BPAD) binCnt[idx] = 0;
}

// ---------------------------------------------------------------------------
// P1: counting-sort 4096 edges into LDS by bin, then coalesced burst writes.
// packed value = (dst<<16)|src  (both < 2^16); bin = v>>23.
__global__ __launch_bounds__(1024) void bin_scatter_kernel(
    const int* __restrict__ esrc_in, const int* __restrict__ edst_in,
    int* __restrict__ binCnt, unsigned int* __restrict__ binBuf)
{
    __shared__ int cntL[NBINS];
    __shared__ int startL[NBINS];
    __shared__ int gbaseL[NBINS];
    __shared__ int s[512];
    __shared__ unsigned int sortedL[P1_EPB];   // 16 KB
    const int tid = threadIdx.x;
    const int e0 = blockIdx.x * P1_EPB;
    const int tcount = (N_EDGES - e0 < P1_EPB) ? (N_EDGES - e0) : P1_EPB;

    for (int i = tid; i < NBINS; i += 1024) cntL[i] = 0;
    __syncthreads();

    // count + local rank
    int e4 = e0 + tid * 4;
    const bool valid = e4 < N_EDGES;
    unsigned int pk[4]; int bb[4], rk[4];
    if (valid) {
        int4 d4 = *(const int4*)(edst_in + e4);
        int4 s4 = *(const int4*)(esrc_in + e4);
        pk[0] = ((unsigned)d4.x << 16) | (unsigned)s4.x;
        pk[1] = ((unsigned)d4.y << 16) | (unsigned)s4.y;
        pk[2] = ((unsigned)d4.z << 16) | (unsigned)s4.z;
        pk[3] = ((unsigned)d4.w << 16) | (unsigned)s4.w;
        bb[0] = d4.x >> 7; bb[1] = d4.y >> 7; bb[2] = d4.z >> 7; bb[3] = d4.w >> 7;
        rk[0] = atomicAdd(&cntL[bb[0]], 1);
        rk[1] = atomicAdd(&cntL[bb[1]], 1);
        rk[2] = atomicAdd(&cntL[bb[2]], 1);
        rk[3] = atomicAdd(&cntL[bb[3]], 1);
    }
    __syncthreads();

    // exclusive scan of cntL (Hillis-Steele over 512)
    if (tid < 512) s[tid] = (tid < NBINS) ? cntL[tid] : 0;
    __syncthreads();
    for (int d = 1; d < 512; d <<= 1) {
        int t = 0;
        if (tid < 512 && tid >= d) t = s[tid - d];
        __syncthreads();
        if (tid < 512) s[tid] += t;
        __syncthreads();
    }
    if (tid < NBINS) {
        startL[tid] = s[tid] - cntL[tid];
        int c = cntL[tid];
        gbaseL[tid] = (c > 0) ? atomicAdd(&binCnt[tid * BPAD], c) : 0;
    }
    __syncthreads();

    // place into LDS sorted by bin
    if (valid) {
        sortedL[startL[bb[0]] + rk[0]] = pk[0];
        sortedL[startL[bb[1]] + rk[1]] = pk[1];
        sortedL[startL[bb[2]] + rk[2]] = pk[2];
        sortedL[startL[bb[3]] + rk[3]] = pk[3];
    }
    __syncthreads();

    // coalesced burst write-out
    for (int i = tid; i < tcount; i += 1024) {
        unsigned int v = sortedL[i];
        int b = (int)(v >> 23);
        int off = gbaseL[b] + (i - startL[b]);
        if (off < BCAP) binBuf[(size_t)b * BCAP + off] = v;
    }
}

// ---------------------------------------------------------------------------
// P2: per-bin adjacency build. LDS slot counters; stores within 16KB window.
__global__ __launch_bounds__(256) void bin_adj_kernel(
    const int* __restrict__ binCnt, const unsigned int* __restrict__ binBuf,
    unsigned short* __restrict__ adj, int* __restrict__ cnt)
{
    __shared__ int cl[NPB];
    const int b = blockIdx.x;
    const int tid = threadIdx.x;
    if (tid < NPB) cl[tid] = 0;
    __syncthreads();
    int ec = binCnt[b * BPAD]; if (ec > BCAP) ec = BCAP;
    const unsigned int* buf = binBuf + (size_t)b * BCAP;
    for (int i = tid; i < ec; i += 256) {
        unsigned int p = buf[i];
        int dl = (int)((p >> 16) & 127u);
        int slot = atomicAdd(&cl[dl], 1);
        if (slot < CAP)
            adj[((size_t)(b * NPB + dl)) * CAP + slot] = (unsigned short)(p & 0xFFFFu);
    }
    __syncthreads();
    if (tid < NPB) {
        int n = b * NPB + tid;
        if (n < N_NODES) cnt[n] = cl[tid];
    }
}

// ---------------------------------------------------------------------------
// agg: NPW nodes per wave. DHALF = row width in bf16.
// adj row packed 2 ushorts/lane -> uint shfl (covers 2*LPN edges).
// NG==1 specialization: every lane owns one row chunk; no cross-group reduce.
template <int DHALF, int NPW>
__global__ __launch_bounds__(256) void agg_kernel(const int* __restrict__ cnt,
                                                  const unsigned short* __restrict__ adj,
                                                  const unsigned short* __restrict__ Xh,
                                                  unsigned short* __restrict__ M)
{
    constexpr int CH  = DHALF / 8;   // uint4 chunks per row (8 or 16)
    constexpr int LPN = 64 / NPW;    // lanes per node (16)
    constexpr int NG  = LPN / CH;    // edge groups per node (2 or 1)
    constexpr int NL  = 16 / NG;     // loads per lane per 16-edge iter (8 or 16)
    const int lane = threadIdx.x & 63;
    const int wv   = threadIdx.x >> 6;
    const int ln   = lane % LPN;     // lane within node
    const int nbl  = lane - ln;      // node's first lane (shfl base)
    const int grp  = ln / CH;        // 0..NG-1
    const int sl   = ln % CH;        // row chunk
    const int n = (blockIdx.x * 4 + wv) * NPW + (lane / LPN);

    int degT = cnt[n];
    int deg  = (degT < CAP) ? degT : CAP;
    unsigned int er32 = ((const unsigned int*)adj)[(size_t)n * (CAP / 2) + ln];
    float a0=0.f,a1=0.f,a2=0.f,a3=0.f,a4=0.f,a5=0.f,a6=0.f,a7=0.f;
    const uint4* gbase = (const uint4*)Xh;
    const int c1 = deg - 1;
    const int lim1 = (2 * LPN >= CAP) ? deg : ((deg < 2 * LPN) ? deg : 2 * LPN);
    for (int e = 0; e < lim1; e += 16) {
        uint4 v[NL]; float mk[NL];
        #pragma unroll
        for (int j = 0; j < NL; ++j) {
            int ee = e + j * NG + grp;
            int eec = (ee < c1) ? ee : c1;
            unsigned int u = __shfl(er32, nbl + (eec >> 1));
            int s = (eec & 1) ? (int)(u >> 16) : (int)(u & 0xFFFFu);
            v[j]  = gbase[(size_t)s * CH + sl];
            mk[j] = (ee < deg) ? 1.f : 0.f;
        }
        #pragma unroll
        for (int j = 0; j < NL; ++j) {
            a0 += mk[j] * bflo(v[j].x); a1 += mk[j] * bfhi(v[j].x);
            a2 += mk[j] * bflo(v[j].y); a3 += mk[j] * bfhi(v[j].y);
            a4 += mk[j] * bflo(v[j].z); a5 += mk[j] * bfhi(v[j].z);
            a6 += mk[j] * bflo(v[j].w); a7 += mk[j] * bfhi(v[j].w);
        }
    }
    if (2 * LPN < CAP) {            // rare tail (deg > 2*LPN)
        for (int e = 2 * LPN; e < deg; e += 16) {
            uint4 v[NL]; float mk[NL];
            #pragma unroll
            for (int j = 0; j < NL; ++j) {
                int ee = e + j * NG + grp;
                int eec = (ee < c1) ? ee : c1;
                int s = (int)adj[(size_t)n * CAP + eec];
                v[j]  = gbase[(size_t)s * CH + sl];
                mk[j] = (ee < deg) ? 1.f : 0.f;
            }
            #pragma unroll
            for (int j = 0; j < NL; ++j) {
                a0 += mk[j] * bflo(v[j].x); a1 += mk[j] * bfhi(v[j].x);
                a2 += mk[j] * bflo(v[j].y); a3 += mk[j] * bfhi(v[j].y);
                a4 += mk[j] * bflo(v[j].z); a5 += mk[j] * bfhi(v[j].z);
                a6 += mk[j] * bflo(v[j].w); a7 += mk[j] * bfhi(v[j].w);
            }
        }
    }
    if (NG > 1) {   // cross-group reduce: partner is lane ^ CH
        a0 += __shfl_xor(a0, CH); a1 += __shfl_xor(a1, CH);
        a2 += __shfl_xor(a2, CH); a3 += __shfl_xor(a3, CH);
        a4 += __shfl_xor(a4, CH); a5 += __shfl_xor(a5, CH);
        a6 += __shfl_xor(a6, CH); a7 += __shfl_xor(a7, CH);
    }

    if (grp == 0) {
        float inv = (degT > 0) ? 1.f / (float)degT : 0.f;
        uint4 p;
        p.x = (unsigned int)f2bf(a0 * inv) | ((unsigned int)f2bf(a1 * inv) << 16);
        p.y = (unsigned int)f2bf(a2 * inv) | ((unsigned int)f2bf(a3 * inv) << 16);
        p.z = (unsigned int)f2bf(a4 * inv) | ((unsigned int)f2bf(a5 * inv) << 16);
        p.w = (unsigned int)f2bf(a6 * inv) | ((unsigned int)f2bf(a7 * inv) << 16);
        ((uint4*)M)[(size_t)n * CH + sl] = p;
    }
}

// ---------------------------------------------------------------------------
// MFMA layer: Out[node][f] = relu(LN([Xh|M] @ Wcat^T + bl)) as bf16
template <int KPAD>
__global__ __launch_bounds__(256) void mfma_layer_kernel(
    const unsigned short* __restrict__ Xh, const unsigned short* __restrict__ M,
    const unsigned short* __restrict__ W,
    const float* __restrict__ bl, const float* __restrict__ g,
    const float* __restrict__ beta,
    unsigned short* __restrict__ Out)
{
    constexpr int DHALF = KPAD / 2;
    const int lane = threadIdx.x & 63;
    const int wv   = threadIdx.x >> 6;
    const int l15  = lane & 15;
    const int l4   = lane >> 4;
    const int row0 = blockIdx.x * 128 + wv * 32;

    int rA0 = row0 + l15;       if (rA0 > N_NODES - 1) rA0 = N_NODES - 1;
    int rA1 = row0 + 16 + l15;  if (rA1 > N_NODES - 1) rA1 = N_NODES - 1;

    f32x4 acc[2][8];
    #pragma unroll
    for (int m = 0; m < 2; ++m)
        #pragma unroll
        for (int n = 0; n < 8; ++n) acc[m][n] = (f32x4){0.f, 0.f, 0.f, 0.f};

    const int kb = l4 * 8;
    #pragma unroll
    for (int ks = 0; ks < KPAD / 32; ++ks) {
        const int k = ks * 32 + kb;
        bf16x8 a0, a1;
        if (ks < DHALF / 32) {
            a0 = *(const bf16x8*)(Xh + (size_t)rA0 * DHALF + k);
            a1 = *(const bf16x8*)(Xh + (size_t)rA1 * DHALF + k);
        } else {
            a0 = *(const bf16x8*)(M + (size_t)rA0 * DHALF + (k - DHALF));
            a1 = *(const bf16x8*)(M + (size_t)rA1 * DHALF + (k - DHALF));
        }
        #pragma unroll
        for (int ni = 0; ni < 8; ++ni) {
            bf16x8 b = *(const bf16x8*)(W + (size_t)(ni * 16 + l15) * KPAD + k);
            acc[0][ni] = __builtin_amdgcn_mfma_f32_16x16x32_bf16(a0, b, acc[0][ni], 0, 0, 0);
            acc[1][ni] = __builtin_amdgcn_mfma_f32_16x16x32_bf16(a1, b, acc[1][ni], 0, 0, 0);
        }
    }

    float blv[8], gv[8], bev[8];
    #pragma unroll
    for (int ni = 0; ni < 8; ++ni) {
        int f = ni * 16 + l15;
        blv[ni] = bl[f]; gv[ni] = g[f]; bev[ni] = beta[f];
    }

    #pragma unroll
    for (int mi = 0; mi < 2; ++mi) {
        #pragma unroll
        for (int r = 0; r < 4; ++r) {
            float v[8];
            float s1 = 0.f, s2 = 0.f;
            #pragma unroll
            for (int ni = 0; ni < 8; ++ni) {
                float t = acc[mi][ni][r] + blv[ni];
                v[ni] = t; s1 += t; s2 += t * t;
            }
            #pragma unroll
            for (int m = 8; m >= 1; m >>= 1) {
                s1 += __shfl_xor(s1, m);
                s2 += __shfl_xor(s2, m);
            }
            float mu   = s1 * (1.f / 128.f);
            float var  = s2 * (1.f / 128.f) - mu * mu;
            float rstd = rsqrtf(var + LN_EPS);
            int node = row0 + mi * 16 + l4 * 4 + r;
            if (node < N_NODES) {
                #pragma unroll
                for (int ni = 0; ni < 8; ++ni) {
                    float o = gv[ni] * (v[ni] - mu) * rstd + bev[ni];
                    o = fmaxf(o, 0.f);
                    Out[(size_t)node * 128 + ni * 16 + l15] = f2bf(o);
                }
            }
        }
    }
}

// ---------------------------------------------------------------------------
// fused pooling (mean+max) + linear head. 1 block / graph, 256 threads.
__global__ __launch_bounds__(256) void poolhead_kernel(const unsigned short* __restrict__ h2,
                                                       const int* __restrict__ starts,
                                                       const float* __restrict__ Wlin,
                                                       const float* __restrict__ blin,
                                                       float* __restrict__ out)
{
    const int g  = blockIdx.x;
    const int j2 = threadIdx.x & 63;   // col pair 2*j2, 2*j2+1
    const int h  = threadIdx.x >> 6;   // row group 0..3
    const int s0 = starts[g], s1 = starts[g + 1];
    float sa = 0.f, sb = 0.f, ma = -INFINITY, mb = -INFINITY;
    const unsigned int* base = (const unsigned int*)h2;   // row stride 64 uints
    int n = s0 + h;
    for (; n + 4 < s1; n += 8) {
        unsigned int u0 = base[(size_t)n * 64 + j2];
        unsigned int u1 = base[(size_t)(n + 4) * 64 + j2];
        float l0 = bflo(u0), h0 = bfhi(u0);
        float l1 = bflo(u1), h1 = bfhi(u1);
        sa += l0 + l1; sb += h0 + h1;
        ma = fmaxf(ma, fmaxf(l0, l1));
        mb = fmaxf(mb, fmaxf(h0, h1));
    }
    if (n < s1) {
        unsigned int u = base[(size_t)n * 64 + j2];
        float lo = bflo(u), hi = bfhi(u);
        sa += lo; sb += hi;
        ma = fmaxf(ma, lo); mb = fmaxf(mb, hi);
    }
    __shared__ float red[4][4][64];
    __shared__ float pooled[256];
    red[h][0][j2] = sa; red[h][1][j2] = sb; red[h][2][j2] = ma; red[h][3][j2] = mb;
    __syncthreads();
    if (h == 0) {
        #pragma unroll
        for (int o = 1; o < 4; ++o) {
            sa += red[o][0][j2]; sb += red[o][1][j2];
            ma = fmaxf(ma, red[o][2][j2]); mb = fmaxf(mb, red[o][3][j2]);
        }
        int c = s1 - s0;
        float inv = (c > 0) ? 1.f / (float)c : 0.f;
        pooled[2 * j2]           = sa * inv;
        pooled[2 * j2 + 1]       = sb * inv;
        pooled[128 + 2 * j2]     = (c > 0) ? ma : 0.f;
        pooled[128 + 2 * j2 + 1] = (c > 0) ? mb : 0.f;
    }
    __syncthreads();
    if (threadIdx.x < 10) {
        const float* w = Wlin + threadIdx.x * 256;
        float acc = blin[threadIdx.x];
        for (int k = 0; k < 256; ++k) acc += pooled[k] * w[k];
        out[g * 10 + threadIdx.x] = acc;
    }
}

// ---------------------------------------------------------------------------
extern "C" void kernel_launch(void* const* d_in, const int* in_sizes, int n_in,
                              void* d_out, int out_size, void* d_ws, size_t ws_size,
                              hipStream_t stream)
{
    const float* x      = (const float*)d_in[0];
    const float* xdims  = (const float*)d_in[1];
    const int*   stt    = (const int*)d_in[2];
    const int*   eidx   = (const int*)d_in[3];
    const int*   batch  = (const int*)d_in[4];
    const float* st_emb = (const float*)d_in[5];
    const float* Wl1 = (const float*)d_in[6];
    const float* bl1 = (const float*)d_in[7];
    const float* Wr1 = (const float*)d_in[8];
    const float* g1  = (const float*)d_in[9];
    const float* be1 = (const float*)d_in[10];
    const float* Wl2 = (const float*)d_in[11];
    const float* bl2 = (const float*)d_in[12];
    const float* Wr2 = (const float*)d_in[13];
    const float* g2  = (const float*)d_in[14];
    const float* be2 = (const float*)d_in[15];
    const float* Wlin = (const float*)d_in[16];
    const float* blin = (const float*)d_in[17];
    float* out = (float*)d_out;

    const int* esrc_in = eidx;
    const int* edst_in = eidx + N_EDGES;

    char* ws = (char*)d_ws;
    size_t o = 0;
    auto carve = [&](size_t bytes) { void* p = ws + o; o = (o + bytes + 255) & ~(size_t)255; return p; };
    unsigned short* Xh1  = (unsigned short*)carve((size_t)N_NODES * 64 * 2);
    unsigned short* M1   = (unsigned short*)carve((size_t)N_NODES * 64 * 2);
    unsigned short* Xh2  = (unsigned short*)carve((size_t)N_NODES * 128 * 2);
    unsigned short* M2   = (unsigned short*)carve((size_t)N_NODES * 128 * 2);
    unsigned short* h2bf = (unsigned short*)carve((size_t)N_NODES * 128 * 2);
    unsigned short* Wc1  = (unsigned short*)carve((size_t)128 * 128 * 2);
    unsigned short* Wc2  = (unsigned short*)carve((size_t)128 * 256 * 2);
    int*            cnt  = (int*)carve((size_t)N_NODES * 4);
    int*          binCnt = (int*)carve((size_t)NBINS * BPAD * 4);
    unsigned int* binBuf = (unsigned int*)carve((size_t)NBINS * BCAP * 4);
    unsigned short* adj  = (unsigned short*)carve((size_t)(NBINS * NPB) * CAP * 2);
    int*          starts = (int*)carve((size_t)(N_GRAPHS + 1) * 4);
    (void)ws_size;

    // 1. prep: Xh1 + weight concat + starts + binCnt zero
    prep_kernel<<<PREP_BLOCKS, 256, 0, stream>>>(
        x, xdims, stt, st_emb, Wl1, Wr1, Wl2, Wr2, batch,
        Xh1, Wc1, Wc2, binCnt, starts);

    // 2. P1: edges -> per-bin buckets (LDS counting sort, coalesced writes)
    bin_scatter_kernel<<<P1_BLOCKS, 1024, 0, stream>>>(
        esrc_in, edst_in, binCnt, binBuf);

    // 3. P2: buckets -> padded adjacency + degrees
    bin_adj_kernel<<<NBINS, 256, 0, stream>>>(binCnt, binBuf, adj, cnt);

    // 4-5. layer 1 (4 nodes/wave)
    agg_kernel<64, 4><<<N_NODES / 16, 256, 0, stream>>>(cnt, adj, Xh1, M1);
    mfma_layer_kernel<128><<<(N_NODES + 127) / 128, 256, 0, stream>>>(
        Xh1, M1, Wc1, bl1, g1, be1, Xh2);

    // 6-7. layer 2 (4 nodes/wave, NG=1)
    agg_kernel<128, 4><<<N_NODES / 16, 256, 0, stream>>>(cnt, adj, Xh2, M2);
    mfma_layer_kernel<256><<<(N_NODES + 127) / 128, 256, 0, stream>>>(
        Xh2, M2, Wc2, bl2, g2, be2, h2bf);

    // 8. fused pooling + head
    poolhead_kernel<<<N_GRAPHS, 256, 0, stream>>>(h2bf, starts, Wlin, blin, out);
}

// Round 14
// 108.313 us; speedup vs baseline: 1.0977x; 1.0977x over previous
//
#include <hip/hip_runtime.h>
#include <hip/hip_bf16.h>
#include <math.h>

#define N_NODES 50000
#define N_EDGES 600000
#define N_GRAPHS 512
#define LN_EPS 1e-5f
#define CAP 64
#define NPB 128                    // nodes per bin
#define NBINS ((N_NODES + NPB - 1) / NPB)   // 391
#define BCAP 2048                  // edges per bin bucket
#define BPAD 16                    // bin counter padding (64B line each)
#define PREP_BLOCKS ((N_NODES * 8 + 255) / 256)

typedef short bf16x8 __attribute__((ext_vector_type(8)));
typedef float f32x4 __attribute__((ext_vector_type(4)));

__device__ __forceinline__ unsigned short f2bf(float f) {
    unsigned int x = __float_as_uint(f);
    return (unsigned short)((x + 0x7fffu + ((x >> 16) & 1u)) >> 16);
}
__device__ __forceinline__ float bflo(unsigned int u) { return __uint_as_float(u << 16); }
__device__ __forceinline__ float bfhi(unsigned int u) { return __uint_as_float(u & 0xffff0000u); }

// ---------------------------------------------------------------------------
// prep: Xh1 build (uint4 stores) + weight concat + starts + binCnt zero
__global__ __launch_bounds__(256) void prep_kernel(
    const float* __restrict__ x, const float* __restrict__ xdims,
    const int* __restrict__ stt, const float* __restrict__ st_emb,
    const float* __restrict__ Wl1, const float* __restrict__ Wr1,
    const float* __restrict__ Wl2, const float* __restrict__ Wr2,
    const int* __restrict__ batch,
    unsigned short* __restrict__ Xh1, unsigned short* __restrict__ Wc1,
    unsigned short* __restrict__ Wc2, int* __restrict__ binCnt,
    int* __restrict__ starts)
{
    int idx = blockIdx.x * 256 + threadIdx.x;

    // job A: Xh1[n][c], 8 cols/thread, one uint4 store
    if (idx < N_NODES * 8) {
        int n = idx >> 3;
        int c0 = (idx & 7) * 8;
        float vv[8];
        #pragma unroll
        for (int j = 0; j < 8; ++j) {
            int c = c0 + j;
            float v;
            if (c < 29)       v = x[n * 29 + c];
            else if (c < 32)  v = xdims[n * 3 + (c - 29)];
            else if (c < 44)  v = st_emb[stt[n] * 12 + (c - 32)];
            else              v = 0.f;
            vv[j] = v;
        }
        uint4 p;
        p.x = (unsigned int)f2bf(vv[0]) | ((unsigned int)f2bf(vv[1]) << 16);
        p.y = (unsigned int)f2bf(vv[2]) | ((unsigned int)f2bf(vv[3]) << 16);
        p.z = (unsigned int)f2bf(vv[4]) | ((unsigned int)f2bf(vv[5]) << 16);
        p.w = (unsigned int)f2bf(vv[6]) | ((unsigned int)f2bf(vv[7]) << 16);
        ((uint4*)Xh1)[idx] = p;
    }
    // job B: Wc1 row f = [Wr1(44) | 0x20 | Wl1(44) | 0x20]
    if (idx < 128 * 128) {
        int f = idx >> 7, k = idx & 127;
        float v;
        if (k < 44)        v = Wr1[f * 44 + k];
        else if (k < 64)   v = 0.f;
        else if (k < 108)  v = Wl1[f * 44 + (k - 64)];
        else               v = 0.f;
        Wc1[idx] = f2bf(v);
    }
    // job C: Wc2 row f = [Wr2(128) | Wl2(128)]
    if (idx < 128 * 256) {
        int f = idx >> 8, k = idx & 255;
        float v = (k < 128) ? Wr2[f * 128 + k] : Wl2[f * 128 + (k - 128)];
        Wc2[idx] = f2bf(v);
    }
    // job D: graph starts from sorted batch
    if (idx < N_NODES) {
        int b = batch[idx];
        int pb = (idx == 0) ? -1 : batch[idx - 1];
        for (int g = pb + 1; g <= b; ++g) starts[g] = idx;
        if (idx == N_NODES - 1)
            for (int g = b + 1; g <= N_GRAPHS; ++g) starts[g] = N_NODES;
    }
    // job E: zero padded bin counters
    if (idx < NBINS * BPAD) binCnt[idx] = 0;
}

// ---------------------------------------------------------------------------
// P1: scatter edges into per-bin buckets. LDS ranks, ~391 global atomics/block.
__global__ __launch_bounds__(1024) void bin_scatter_kernel(
    const int* __restrict__ esrc_in, const int* __restrict__ edst_in,
    int* __restrict__ binCnt, unsigned int* __restrict__ binBuf)
{
    __shared__ int cntL[NBINS];
    __shared__ int gbaseL[NBINS];
    const int tid = threadIdx.x;
    for (int i = tid; i < NBINS; i += 1024) cntL[i] = 0;
    __syncthreads();

    int e4 = (blockIdx.x * 1024 + tid) * 4;
    int4 d4, s4; int b0=0,b1=0,b2=0,b3=0, r0=0,r1=0,r2=0,r3=0;
    const bool valid = e4 < N_EDGES;
    if (valid) {
        d4 = *(const int4*)(edst_in + e4);
        s4 = *(const int4*)(esrc_in + e4);
        b0 = d4.x >> 7; b1 = d4.y >> 7; b2 = d4.z >> 7; b3 = d4.w >> 7;
        r0 = atomicAdd(&cntL[b0], 1);
        r1 = atomicAdd(&cntL[b1], 1);
        r2 = atomicAdd(&cntL[b2], 1);
        r3 = atomicAdd(&cntL[b3], 1);
    }
    __syncthreads();
    for (int i = tid; i < NBINS; i += 1024) {
        int c = cntL[i];
        gbaseL[i] = (c > 0) ? atomicAdd(&binCnt[i * BPAD], c) : 0;
    }
    __syncthreads();
    if (valid) {
        int p0 = gbaseL[b0] + r0, p1 = gbaseL[b1] + r1;
        int p2 = gbaseL[b2] + r2, p3 = gbaseL[b3] + r3;
        if (p0 < BCAP) binBuf[(size_t)b0 * BCAP + p0] = (((unsigned)d4.x & 127u) << 16) | (unsigned)s4.x;
        if (p1 < BCAP) binBuf[(size_t)b1 * BCAP + p1] = (((unsigned)d4.y & 127u) << 16) | (unsigned)s4.y;
        if (p2 < BCAP) binBuf[(size_t)b2 * BCAP + p2] = (((unsigned)d4.z & 127u) << 16) | (unsigned)s4.z;
        if (p3 < BCAP) binBuf[(size_t)b3 * BCAP + p3] = (((unsigned)d4.w & 127u) << 16) | (unsigned)s4.w;
    }
}

// ---------------------------------------------------------------------------
// P2: per-bin adjacency build. LDS slot counters; stores within 16KB window.
__global__ __launch_bounds__(256) void bin_adj_kernel(
    const int* __restrict__ binCnt, const unsigned int* __restrict__ binBuf,
    unsigned short* __restrict__ adj, int* __restrict__ cnt)
{
    __shared__ int cl[NPB];
    const int b = blockIdx.x;
    const int tid = threadIdx.x;
    if (tid < NPB) cl[tid] = 0;
    __syncthreads();
    int ec = binCnt[b * BPAD]; if (ec > BCAP) ec = BCAP;
    const unsigned int* buf = binBuf + (size_t)b * BCAP;
    for (int i = tid; i < ec; i += 256) {
        unsigned int p = buf[i];
        int dl = (int)(p >> 16);
        int slot = atomicAdd(&cl[dl], 1);
        if (slot < CAP)
            adj[((size_t)(b * NPB + dl)) * CAP + slot] = (unsigned short)(p & 0xFFFFu);
    }
    __syncthreads();
    if (tid < NPB) {
        int n = b * NPB + tid;
        if (n < N_NODES) cnt[n] = cl[tid];
    }
}

// ---------------------------------------------------------------------------
// agg: NPW nodes per wave. DHALF = row width in bf16.
// adj row packed 2 ushorts/lane -> uint shfl (covers 2*LPN edges).
template <int DHALF, int NPW>
__global__ __launch_bounds__(256) void agg_kernel(const int* __restrict__ cnt,
                                                  const unsigned short* __restrict__ adj,
                                                  const unsigned short* __restrict__ Xh,
                                                  unsigned short* __restrict__ M)
{
    constexpr int CH  = DHALF / 8;   // uint4 chunks per row (8 or 16)
    constexpr int LPN = 64 / NPW;    // lanes per node (16 or 32)
    constexpr int NG  = LPN / CH;    // edge groups per node (= 2)
    constexpr int NL  = 16 / NG;     // loads per lane per 16-edge iter (= 8)
    const int lane = threadIdx.x & 63;
    const int wv   = threadIdx.x >> 6;
    const int ln   = lane % LPN;     // lane within node
    const int nbl  = lane - ln;      // node's first lane (shfl base)
    const int grp  = ln / CH;        // 0..NG-1
    const int sl   = ln % CH;        // row chunk
    const int n = (blockIdx.x * 4 + wv) * NPW + (lane / LPN);

    int degT = cnt[n];
    int deg  = (degT < CAP) ? degT : CAP;
    unsigned int er32 = ((const unsigned int*)adj)[(size_t)n * (CAP / 2) + ln];
    float a0=0.f,a1=0.f,a2=0.f,a3=0.f,a4=0.f,a5=0.f,a6=0.f,a7=0.f;
    const uint4* gbase = (const uint4*)Xh;
    const int c1 = deg - 1;
    const int lim1 = (2 * LPN >= CAP) ? deg : ((deg < 2 * LPN) ? deg : 2 * LPN);
    for (int e = 0; e < lim1; e += 16) {
        uint4 v[NL]; float mk[NL];
        #pragma unroll
        for (int j = 0; j < NL; ++j) {
            int ee = e + j * NG + grp;
            int eec = (ee < c1) ? ee : c1;
            unsigned int u = __shfl(er32, nbl + (eec >> 1));
            int s = (eec & 1) ? (int)(u >> 16) : (int)(u & 0xFFFFu);
            v[j]  = gbase[(size_t)s * CH + sl];
            mk[j] = (ee < deg) ? 1.f : 0.f;
        }
        #pragma unroll
        for (int j = 0; j < NL; ++j) {
            a0 += mk[j] * bflo(v[j].x); a1 += mk[j] * bfhi(v[j].x);
            a2 += mk[j] * bflo(v[j].y); a3 += mk[j] * bfhi(v[j].y);
            a4 += mk[j] * bflo(v[j].z); a5 += mk[j] * bfhi(v[j].z);
            a6 += mk[j] * bflo(v[j].w); a7 += mk[j] * bfhi(v[j].w);
        }
    }
    if (2 * LPN < CAP) {            // rare tail (deg > 2*LPN)
        for (int e = 2 * LPN; e < deg; e += 16) {
            uint4 v[NL]; float mk[NL];
            #pragma unroll
            for (int j = 0; j < NL; ++j) {
                int ee = e + j * NG + grp;
                int eec = (ee < c1) ? ee : c1;
                int s = (int)adj[(size_t)n * CAP + eec];
                v[j]  = gbase[(size_t)s * CH + sl];
                mk[j] = (ee < deg) ? 1.f : 0.f;
            }
            #pragma unroll
            for (int j = 0; j < NL; ++j) {
                a0 += mk[j] * bflo(v[j].x); a1 += mk[j] * bfhi(v[j].x);
                a2 += mk[j] * bflo(v[j].y); a3 += mk[j] * bfhi(v[j].y);
                a4 += mk[j] * bflo(v[j].z); a5 += mk[j] * bfhi(v[j].z);
                a6 += mk[j] * bflo(v[j].w); a7 += mk[j] * bfhi(v[j].w);
            }
        }
    }
    // cross-group reduce (NG == 2): partner is lane ^ CH
    a0 += __shfl_xor(a0, CH); a1 += __shfl_xor(a1, CH);
    a2 += __shfl_xor(a2, CH); a3 += __shfl_xor(a3, CH);
    a4 += __shfl_xor(a4, CH); a5 += __shfl_xor(a5, CH);
    a6 += __shfl_xor(a6, CH); a7 += __shfl_xor(a7, CH);

    if (grp == 0) {
        float inv = (degT > 0) ? 1.f / (float)degT : 0.f;
        uint4 p;
        p.x = (unsigned int)f2bf(a0 * inv) | ((unsigned int)f2bf(a1 * inv) << 16);
        p.y = (unsigned int)f2bf(a2 * inv) | ((unsigned int)f2bf(a3 * inv) << 16);
        p.z = (unsigned int)f2bf(a4 * inv) | ((unsigned int)f2bf(a5 * inv) << 16);
        p.w = (unsigned int)f2bf(a6 * inv) | ((unsigned int)f2bf(a7 * inv) << 16);
        ((uint4*)M)[(size_t)n * CH + sl] = p;
    }
}

// ---------------------------------------------------------------------------
// MFMA layer: Out[node][f] = relu(LN([Xh|M] @ Wcat^T + bl)) as bf16
// 64 nodes per wave (acc[4][8]) -> halves per-wave W re-reads.
template <int KPAD>
__global__ __launch_bounds__(256) void mfma_layer_kernel(
    const unsigned short* __restrict__ Xh, const unsigned short* __restrict__ M,
    const unsigned short* __restrict__ W,
    const float* __restrict__ bl, const float* __restrict__ g,
    const float* __restrict__ beta,
    unsigned short* __restrict__ Out)
{
    constexpr int DHALF = KPAD / 2;
    const int lane = threadIdx.x & 63;
    const int wv   = threadIdx.x >> 6;
    const int l15  = lane & 15;
    const int l4   = lane >> 4;
    const int row0 = blockIdx.x * 256 + wv * 64;

    int rA[4];
    #pragma unroll
    for (int mi = 0; mi < 4; ++mi) {
        int r = row0 + mi * 16 + l15;
        rA[mi] = (r > N_NODES - 1) ? (N_NODES - 1) : r;
    }

    f32x4 acc[4][8];
    #pragma unroll
    for (int m = 0; m < 4; ++m)
        #pragma unroll
        for (int n = 0; n < 8; ++n) acc[m][n] = (f32x4){0.f, 0.f, 0.f, 0.f};

    const int kb = l4 * 8;
    #pragma unroll
    for (int ks = 0; ks < KPAD / 32; ++ks) {
        const int k = ks * 32 + kb;
        bf16x8 a[4];
        if (ks < DHALF / 32) {
            #pragma unroll
            for (int mi = 0; mi < 4; ++mi)
                a[mi] = *(const bf16x8*)(Xh + (size_t)rA[mi] * DHALF + k);
        } else {
            #pragma unroll
            for (int mi = 0; mi < 4; ++mi)
                a[mi] = *(const bf16x8*)(M + (size_t)rA[mi] * DHALF + (k - DHALF));
        }
        #pragma unroll
        for (int ni = 0; ni < 8; ++ni) {
            bf16x8 b = *(const bf16x8*)(W + (size_t)(ni * 16 + l15) * KPAD + k);
            #pragma unroll
            for (int mi = 0; mi < 4; ++mi)
                acc[mi][ni] = __builtin_amdgcn_mfma_f32_16x16x32_bf16(a[mi], b, acc[mi][ni], 0, 0, 0);
        }
    }

    float blv[8], gv[8], bev[8];
    #pragma unroll
    for (int ni = 0; ni < 8; ++ni) {
        int f = ni * 16 + l15;
        blv[ni] = bl[f]; gv[ni] = g[f]; bev[ni] = beta[f];
    }

    #pragma unroll
    for (int mi = 0; mi < 4; ++mi) {
        #pragma unroll
        for (int r = 0; r < 4; ++r) {
            float v[8];
            float s1 = 0.f, s2 = 0.f;
            #pragma unroll
            for (int ni = 0; ni < 8; ++ni) {
                float t = acc[mi][ni][r] + blv[ni];
                v[ni] = t; s1 += t; s2 += t * t;
            }
            #pragma unroll
            for (int m = 8; m >= 1; m >>= 1) {
                s1 += __shfl_xor(s1, m);
                s2 += __shfl_xor(s2, m);
            }
            float mu   = s1 * (1.f / 128.f);
            float var  = s2 * (1.f / 128.f) - mu * mu;
            float rstd = rsqrtf(var + LN_EPS);
            int node = row0 + mi * 16 + l4 * 4 + r;
            if (node < N_NODES) {
                #pragma unroll
                for (int ni = 0; ni < 8; ++ni) {
                    float o = gv[ni] * (v[ni] - mu) * rstd + bev[ni];
                    o = fmaxf(o, 0.f);
                    Out[(size_t)node * 128 + ni * 16 + l15] = f2bf(o);
                }
            }
        }
    }
}

// ---------------------------------------------------------------------------
// fused pooling (mean+max) + linear head. 1 block / graph, 256 threads.
__global__ __launch_bounds__(256) void poolhead_kernel(const unsigned short* __restrict__ h2,
                                                       const int* __restrict__ starts,
                                                       const float* __restrict__ Wlin,
                                                       const float* __restrict__ blin,
                                                       float* __restrict__ out)
{
    const int g  = blockIdx.x;
    const int j2 = threadIdx.x & 63;   // col pair 2*j2, 2*j2+1
    const int h  = threadIdx.x >> 6;   // row group 0..3
    const int s0 = starts[g], s1 = starts[g + 1];
    float sa = 0.f, sb = 0.f, ma = -INFINITY, mb = -INFINITY;
    const unsigned int* base = (const unsigned int*)h2;   // row stride 64 uints
    int n = s0 + h;
    for (; n + 4 < s1; n += 8) {
        unsigned int u0 = base[(size_t)n * 64 + j2];
        unsigned int u1 = base[(size_t)(n + 4) * 64 + j2];
        float l0 = bflo(u0), h0 = bfhi(u0);
        float l1 = bflo(u1), h1 = bfhi(u1);
        sa += l0 + l1; sb += h0 + h1;
        ma = fmaxf(ma, fmaxf(l0, l1));
        mb = fmaxf(mb, fmaxf(h0, h1));
    }
    if (n < s1) {
        unsigned int u = base[(size_t)n * 64 + j2];
        float lo = bflo(u), hi = bfhi(u);
        sa += lo; sb += hi;
        ma = fmaxf(ma, lo); mb = fmaxf(mb, hi);
    }
    __shared__ float red[4][4][64];
    __shared__ float pooled[256];
    red[h][0][j2] = sa; red[h][1][j2] = sb; red[h][2][j2] = ma; red[h][3][j2] = mb;
    __syncthreads();
    if (h == 0) {
        #pragma unroll
        for (int o = 1; o < 4; ++o) {
            sa += red[o][0][j2]; sb += red[o][1][j2];
            ma = fmaxf(ma, red[o][2][j2]); mb = fmaxf(mb, red[o][3][j2]);
        }
        int c = s1 - s0;
        float inv = (c > 0) ? 1.f / (float)c : 0.f;
        pooled[2 * j2]           = sa * inv;
        pooled[2 * j2 + 1]       = sb * inv;
        pooled[128 + 2 * j2]     = (c > 0) ? ma : 0.f;
        pooled[128 + 2 * j2 + 1] = (c > 0) ? mb : 0.f;
    }
    __syncthreads();
    if (threadIdx.x < 10) {
        const float* w = Wlin + threadIdx.x * 256;
        float acc = blin[threadIdx.x];
        for (int k = 0; k < 256; ++k) acc += pooled[k] * w[k];
        out[g * 10 + threadIdx.x] = acc;
    }
}

// ---------------------------------------------------------------------------
extern "C" void kernel_launch(void* const* d_in, const int* in_sizes, int n_in,
                              void* d_out, int out_size, void* d_ws, size_t ws_size,
                              hipStream_t stream)
{
    const float* x      = (const float*)d_in[0];
    const float* xdims  = (const float*)d_in[1];
    const int*   stt    = (const int*)d_in[2];
    const int*   eidx   = (const int*)d_in[3];
    const int*   batch  = (const int*)d_in[4];
    const float* st_emb = (const float*)d_in[5];
    const float* Wl1 = (const float*)d_in[6];
    const float* bl1 = (const float*)d_in[7];
    const float* Wr1 = (const float*)d_in[8];
    const float* g1  = (const float*)d_in[9];
    const float* be1 = (const float*)d_in[10];
    const float* Wl2 = (const float*)d_in[11];
    const float* bl2 = (const float*)d_in[12];
    const float* Wr2 = (const float*)d_in[13];
    const float* g2  = (const float*)d_in[14];
    const float* be2 = (const float*)d_in[15];
    const float* Wlin = (const float*)d_in[16];
    const float* blin = (const float*)d_in[17];
    float* out = (float*)d_out;

    const int* esrc_in = eidx;
    const int* edst_in = eidx + N_EDGES;

    char* ws = (char*)d_ws;
    size_t o = 0;
    auto carve = [&](size_t bytes) { void* p = ws + o; o = (o + bytes + 255) & ~(size_t)255; return p; };
    unsigned short* Xh1  = (unsigned short*)carve((size_t)N_NODES * 64 * 2);
    unsigned short* M1   = (unsigned short*)carve((size_t)N_NODES * 64 * 2);
    unsigned short* Xh2  = (unsigned short*)carve((size_t)N_NODES * 128 * 2);
    unsigned short* M2   = (unsigned short*)carve((size_t)N_NODES * 128 * 2);
    unsigned short* h2bf = (unsigned short*)carve((size_t)N_NODES * 128 * 2);
    unsigned short* Wc1  = (unsigned short*)carve((size_t)128 * 128 * 2);
    unsigned short* Wc2  = (unsigned short*)carve((size_t)128 * 256 * 2);
    int*            cnt  = (int*)carve((size_t)N_NODES * 4);
    int*          binCnt = (int*)carve((size_t)NBINS * BPAD * 4);
    unsigned int* binBuf = (unsigned int*)carve((size_t)NBINS * BCAP * 4);
    unsigned short* adj  = (unsigned short*)carve((size_t)(NBINS * NPB) * CAP * 2);
    int*          starts = (int*)carve((size_t)(N_GRAPHS + 1) * 4);
    (void)ws_size;

    // 1. prep: Xh1 + weight concat + starts + binCnt zero
    prep_kernel<<<PREP_BLOCKS, 256, 0, stream>>>(
        x, xdims, stt, st_emb, Wl1, Wr1, Wl2, Wr2, batch,
        Xh1, Wc1, Wc2, binCnt, starts);

    // 2. P1: edges -> per-bin buckets (simple rank-scatter, round-12 proven)
    bin_scatter_kernel<<<(N_EDGES / 4 + 1023) / 1024, 1024, 0, stream>>>(
        esrc_in, edst_in, binCnt, binBuf);

    // 3. P2: buckets -> padded adjacency + degrees
    bin_adj_kernel<<<NBINS, 256, 0, stream>>>(binCnt, binBuf, adj, cnt);

    // 4-5. layer 1 (4 nodes/wave agg; 64 nodes/wave mfma)
    agg_kernel<64, 4><<<N_NODES / 16, 256, 0, stream>>>(cnt, adj, Xh1, M1);
    mfma_layer_kernel<128><<<(N_NODES + 255) / 256, 256, 0, stream>>>(
        Xh1, M1, Wc1, bl1, g1, be1, Xh2);

    // 6-7. layer 2 (2 nodes/wave agg; 64 nodes/wave mfma)
    agg_kernel<128, 2><<<N_NODES / 8, 256, 0, stream>>>(cnt, adj, Xh2, M2);
    mfma_layer_kernel<256><<<(N_NODES + 255) / 256, 256, 0, stream>>>(
        Xh2, M2, Wc2, bl2, g2, be2, h2bf);

    // 8. fused pooling + head
    poolhead_kernel<<<N_GRAPHS, 256, 0, stream>>>(h2bf, starts, Wlin, blin, out);
}